// Round 4
// baseline (218.662 us; speedup 1.0000x reference)
//
#include <hip/hip_runtime.h>
#include <hip/hip_bf16.h>

// Windowed attention smoothing via MFMA — barrier-free, per-wave autonomous.
// rows=200000, RANK=64, WINDOW=11. Block=256 (4 waves), 16 rows/wave,
// ONE 64-row tile per block (grid = rows/64 = 3125). __launch_bounds__(256,8)
// holds VGPR <= 64 so 8 blocks/CU (32 waves/CU) are resident — the round-3
// profile showed a latency-bound kernel at 35% occupancy; TLP is the fix.
//
// Per wave (rows rw..rw+15):
//   - A fragments (M1 rows + 32-row band) loaded DIRECTLY from global fp32,
//     converted to bf16 in regs (no staging barriers, all loads in flight)
//   - M1: V1 = tanh(A@W^T + b)   8x mfma_16x16x32_bf16
//   - V1 -> per-wave LDS (B-frag relayout for M2)
//   - M2: banded scores S = Aband@V1^T   4x mfma -> per-wave LDS scatter
//   - softmax over 11-band per column (LDS broadcast reads, redundant per quad)
//   - P4: out = P*window in fp32 VALU, probs broadcast via static v_readlane
// No __syncthreads: LDS regions are wave-private; DS pipe is in-order per wave.

constexpr int RANK   = 64;
constexpr int WINDOW = 11;
constexpr int PAD    = 5;
constexpr int TILE   = 16;   // rows per wave
constexpr int BLOCK  = 256;  // 4 waves
constexpr int TR     = 64;   // rows per block

typedef short short8  __attribute__((ext_vector_type(8)));
typedef float float4v __attribute__((ext_vector_type(4)));

constexpr int V1_S = 72;  // bf16 elems per V1 row (144B, 16B-aligned, 2-way max)
constexpr int SC_S = 18;  // f32 elems per Sc row (breaks pow2)

__device__ __forceinline__ short8 cvt_bf8(float4 a, float4 b) {
    union { short8 s; __hip_bfloat162 h[4]; } u;
    u.h[0] = __float22bfloat162_rn(make_float2(a.x, a.y));
    u.h[1] = __float22bfloat162_rn(make_float2(a.z, a.w));
    u.h[2] = __float22bfloat162_rn(make_float2(b.x, b.y));
    u.h[3] = __float22bfloat162_rn(make_float2(b.z, b.w));
    return u.s;
}

// Load one MFMA A-fragment half (8 cols) of a global fp32 row, bf16-convert.
__device__ __forceinline__ short8 load_afrag(const float* __restrict__ A,
                                             int row, int col0, int rows) {
    if ((unsigned)row < (unsigned)rows) {
        const float4* p = (const float4*)(A + (size_t)row * RANK + col0);
        return cvt_bf8(p[0], p[1]);
    }
    return (short8)0;   // zero-pad rows (matches jnp.pad semantics: score 0)
}

__device__ __forceinline__ float fast_tanh(float x) {
    return 1.0f - 2.0f / (1.0f + __expf(2.0f * x));
}

__global__ __launch_bounds__(BLOCK, 8) void attn_win_kernel(
    const float* __restrict__ A,   // (rows, 64)
    const float* __restrict__ W,   // (64, 64) row-major (out,in)
    const float* __restrict__ b,   // (64,)
    float* __restrict__ out,       // (rows, 64)
    int rows)
{
    __shared__ __align__(16) __hip_bfloat16 V1[4][TILE][V1_S];  // 9216 B
    __shared__ __align__(16) float          Sc[4][32][SC_S];    // 9216 B

    const int lane = threadIdx.x & 63;
    const int wv   = threadIdx.x >> 6;
    const int m16  = lane & 15;
    const int quad = lane >> 4;
    const int rw   = blockIdx.x * TR + wv * TILE;   // this wave's rows

    // ---- W fragments + bias (per-wave conversion, one tile per block) ----
    short8 wfrag[4][2];  // [ct][kf]: W[n=ct*16+m16][kf*32 + quad*8 + j]
    #pragma unroll
    for (int ct = 0; ct < 4; ct++)
        #pragma unroll
        for (int kf = 0; kf < 2; kf++) {
            const float4* p =
                (const float4*)(W + (ct * 16 + m16) * RANK + kf * 32 + quad * 8);
            wfrag[ct][kf] = cvt_bf8(p[0], p[1]);
        }
    float bias[4];
    #pragma unroll
    for (int ct = 0; ct < 4; ct++) bias[ct] = b[ct * 16 + m16];

    // ---- fragment loads, all independent & in flight ----
    short8 abnd[2][2];  // band rows rw-5+it*16+m16 (band idx i=it*16+m16)
    short8 am1[2];      // M1 rows rw+m16
    #pragma unroll
    for (int it = 0; it < 2; it++)
        #pragma unroll
        for (int kf = 0; kf < 2; kf++)
            abnd[it][kf] = load_afrag(A, rw - PAD + it * 16 + m16,
                                      kf * 32 + quad * 8, rows);
    #pragma unroll
    for (int kf = 0; kf < 2; kf++)
        am1[kf] = load_afrag(A, rw + m16, kf * 32 + quad * 8, rows);

    // ---- M1: V1 = tanh(A[rw..rw+15] @ W^T + b) ----
    float4v acc[4];
    #pragma unroll
    for (int ct = 0; ct < 4; ct++)
        acc[ct] = (float4v){bias[ct], bias[ct], bias[ct], bias[ct]};
    #pragma unroll
    for (int kf = 0; kf < 2; kf++)
        #pragma unroll
        for (int ct = 0; ct < 4; ct++)
            acc[ct] = __builtin_amdgcn_mfma_f32_16x16x32_bf16(
                am1[kf], wfrag[ct][kf], acc[ct], 0, 0, 0);
    // epilogue: element (row q=quad*4+rg, col c=ct*16+m16) -> V1[q][c]
    #pragma unroll
    for (int ct = 0; ct < 4; ct++)
        #pragma unroll
        for (int rg = 0; rg < 4; rg++)
            V1[wv][quad * 4 + rg][ct * 16 + m16] =
                __float2bfloat16(fast_tanh(acc[ct][rg]));

    // ---- M2: S[i][q] = dot(Aband[i], v1[q]) ----
    float4v sacc[2];
    sacc[0] = (float4v){0.f, 0.f, 0.f, 0.f};
    sacc[1] = (float4v){0.f, 0.f, 0.f, 0.f};
    #pragma unroll
    for (int kf = 0; kf < 2; kf++) {
        const short8 bfr = *(const short8*)&V1[wv][m16][kf * 32 + quad * 8];
        #pragma unroll
        for (int it = 0; it < 2; it++)
            sacc[it] = __builtin_amdgcn_mfma_f32_16x16x32_bf16(
                abnd[it][kf], bfr, sacc[it], 0, 0, 0);
    }
    // scatter S (i = it*16+quad*4+rg, q = m16); rows 26..31 are dead
    #pragma unroll
    for (int it = 0; it < 2; it++)
        #pragma unroll
        for (int rg = 0; rg < 4; rg++)
            Sc[wv][it * 16 + quad * 4 + rg][m16] = sacc[it][rg];

    // ---- softmax over band i in [q, q+10] of column q=m16 ----
    // (redundant across quads; broadcast LDS reads; lane rr holds row rw+rr's p)
    float p[WINDOW];
    {
        float s[WINDOW];
        float mx = -1e30f;
        #pragma unroll
        for (int w = 0; w < WINDOW; w++) {
            s[w] = Sc[wv][m16 + w][m16];
            mx = fmaxf(mx, s[w]);
        }
        float den = 0.0f;
        #pragma unroll
        for (int w = 0; w < WINDOW; w++) {
            p[w] = __expf((s[w] - mx) * 0.125f);  // 1/sqrt(64) folded in
            den += p[w];
        }
        const float rden = __fdividef(1.0f, den);
        #pragma unroll
        for (int w = 0; w < WINDOW; w++) p[w] *= rden;
    }

    // ---- P4: out[rw+rr][lane] = sum_w p[rr][w] * A[rw+rr-5+w][lane] ----
    float aw[26];  // fp32 window, coalesced dword loads, uniform guards
    #pragma unroll
    for (int s = 0; s < 26; s++) {
        const int gr = rw - PAD + s;
        aw[s] = ((unsigned)gr < (unsigned)rows)
                    ? A[(size_t)gr * RANK + lane] : 0.0f;
    }
    #pragma unroll
    for (int rr = 0; rr < TILE; rr++) {
        float o = 0.0f;
        #pragma unroll
        for (int w = 0; w < WINDOW; w++) {
            const float pw = __uint_as_float(
                __builtin_amdgcn_readlane(__float_as_uint(p[w]), rr));
            o = fmaf(pw, aw[rr + w], o);
        }
        if (rw + rr < rows)
            out[(size_t)(rw + rr) * RANK + lane] = o;
    }
}

extern "C" void kernel_launch(void* const* d_in, const int* in_sizes, int n_in,
                              void* d_out, int out_size, void* d_ws, size_t ws_size,
                              hipStream_t stream) {
    const float* A = (const float*)d_in[0];
    const float* W = (const float*)d_in[1];
    const float* b = (const float*)d_in[2];
    float* out = (float*)d_out;

    const int rows   = in_sizes[0] / RANK;
    const int blocks = (rows + TR - 1) / TR;   // one 64-row tile per block

    hipLaunchKernelGGL(attn_win_kernel, dim3(blocks), dim3(BLOCK), 0, stream,
                       A, W, b, out, rows);
}

// Round 5
// 140.963 us; speedup vs baseline: 1.5512x; 1.5512x over previous
//
#include <hip/hip_runtime.h>
#include <hip/hip_bf16.h>

// Windowed attention smoothing via MFMA — barrier-free, per-wave autonomous.
// rows=200000, RANK=64, WINDOW=11. Block=256 (4 waves), 16 rows/wave,
// ONE 64-row tile per block (grid = rows/64 = 3125).
//
// Occupancy note (round-4 lesson): __launch_bounds__(256,8) forced the
// unified VGPR+AGPR budget to 64 -> arch side squeezed to 32 -> ~380 MB of
// scratch spill traffic per dispatch (WRITE_SIZE 288 MB). With (256,4) the
// compiler naturally lands at ~64 total VGPR (round-3 evidence), which BY
// ITSELF permits 8 waves/SIMD; the large grid (3125 blocks) supplies the
// blocks the round-3 persistent grid (4 blocks/CU) withheld.
//
// Per wave (rows rw..rw+15):
//   - A fragments (M1 rows + 32-row band) loaded DIRECTLY from global fp32,
//     converted to bf16 in regs (no staging barriers, all loads in flight)
//   - M1: V1 = tanh(A@W^T + b)   8x mfma_16x16x32_bf16
//   - V1 -> per-wave LDS (B-frag relayout for M2)
//   - M2: banded scores S = Aband@V1^T   4x mfma -> per-wave LDS scatter
//   - softmax over 11-band per column (LDS broadcast reads, redundant per quad)
//   - P4: out = P*window in fp32 VALU, probs broadcast via static v_readlane
// No __syncthreads: LDS regions are wave-private; DS pipe is in-order per wave.

constexpr int RANK   = 64;
constexpr int WINDOW = 11;
constexpr int PAD    = 5;
constexpr int TILE   = 16;   // rows per wave
constexpr int BLOCK  = 256;  // 4 waves
constexpr int TR     = 64;   // rows per block

typedef short short8  __attribute__((ext_vector_type(8)));
typedef float float4v __attribute__((ext_vector_type(4)));

constexpr int V1_S = 72;  // bf16 elems per V1 row (144B, 16B-aligned, 2-way max)
constexpr int SC_S = 18;  // f32 elems per Sc row (breaks pow2)

__device__ __forceinline__ short8 cvt_bf8(float4 a, float4 b) {
    union { short8 s; __hip_bfloat162 h[4]; } u;
    u.h[0] = __float22bfloat162_rn(make_float2(a.x, a.y));
    u.h[1] = __float22bfloat162_rn(make_float2(a.z, a.w));
    u.h[2] = __float22bfloat162_rn(make_float2(b.x, b.y));
    u.h[3] = __float22bfloat162_rn(make_float2(b.z, b.w));
    return u.s;
}

// Load one MFMA A-fragment half (8 cols) of a global fp32 row, bf16-convert.
__device__ __forceinline__ short8 load_afrag(const float* __restrict__ A,
                                             int row, int col0, int rows) {
    if ((unsigned)row < (unsigned)rows) {
        const float4* p = (const float4*)(A + (size_t)row * RANK + col0);
        return cvt_bf8(p[0], p[1]);
    }
    return (short8)0;   // zero-pad rows (matches jnp.pad semantics: score 0)
}

__device__ __forceinline__ float fast_tanh(float x) {
    return 1.0f - 2.0f / (1.0f + __expf(2.0f * x));
}

__global__ __launch_bounds__(BLOCK, 4) void attn_win_kernel(
    const float* __restrict__ A,   // (rows, 64)
    const float* __restrict__ W,   // (64, 64) row-major (out,in)
    const float* __restrict__ b,   // (64,)
    float* __restrict__ out,       // (rows, 64)
    int rows)
{
    __shared__ __align__(16) __hip_bfloat16 V1[4][TILE][V1_S];  // 9216 B
    __shared__ __align__(16) float          Sc[4][32][SC_S];    // 9216 B

    const int lane = threadIdx.x & 63;
    const int wv   = threadIdx.x >> 6;
    const int m16  = lane & 15;
    const int quad = lane >> 4;
    const int rw   = blockIdx.x * TR + wv * TILE;   // this wave's rows

    // ---- W fragments + bias ----
    short8 wfrag[4][2];  // [ct][kf]: W[n=ct*16+m16][kf*32 + quad*8 + j]
    #pragma unroll
    for (int ct = 0; ct < 4; ct++)
        #pragma unroll
        for (int kf = 0; kf < 2; kf++) {
            const float4* p =
                (const float4*)(W + (ct * 16 + m16) * RANK + kf * 32 + quad * 8);
            wfrag[ct][kf] = cvt_bf8(p[0], p[1]);
        }
    float bias[4];
    #pragma unroll
    for (int ct = 0; ct < 4; ct++) bias[ct] = b[ct * 16 + m16];

    // ---- fragment loads, all independent & in flight ----
    short8 abnd[2][2];  // band rows rw-5+it*16+m16 (band idx i=it*16+m16)
    short8 am1[2];      // M1 rows rw+m16
    #pragma unroll
    for (int it = 0; it < 2; it++)
        #pragma unroll
        for (int kf = 0; kf < 2; kf++)
            abnd[it][kf] = load_afrag(A, rw - PAD + it * 16 + m16,
                                      kf * 32 + quad * 8, rows);
    #pragma unroll
    for (int kf = 0; kf < 2; kf++)
        am1[kf] = load_afrag(A, rw + m16, kf * 32 + quad * 8, rows);

    // ---- M1: V1 = tanh(A[rw..rw+15] @ W^T + b) ----
    float4v acc[4];
    #pragma unroll
    for (int ct = 0; ct < 4; ct++)
        acc[ct] = (float4v){bias[ct], bias[ct], bias[ct], bias[ct]};
    #pragma unroll
    for (int kf = 0; kf < 2; kf++)
        #pragma unroll
        for (int ct = 0; ct < 4; ct++)
            acc[ct] = __builtin_amdgcn_mfma_f32_16x16x32_bf16(
                am1[kf], wfrag[ct][kf], acc[ct], 0, 0, 0);
    // epilogue: element (row q=quad*4+rg, col c=ct*16+m16) -> V1[q][c]
    #pragma unroll
    for (int ct = 0; ct < 4; ct++)
        #pragma unroll
        for (int rg = 0; rg < 4; rg++)
            V1[wv][quad * 4 + rg][ct * 16 + m16] =
                __float2bfloat16(fast_tanh(acc[ct][rg]));

    // ---- M2: S[i][q] = dot(Aband[i], v1[q]) ----
    float4v sacc[2];
    sacc[0] = (float4v){0.f, 0.f, 0.f, 0.f};
    sacc[1] = (float4v){0.f, 0.f, 0.f, 0.f};
    #pragma unroll
    for (int kf = 0; kf < 2; kf++) {
        const short8 bfr = *(const short8*)&V1[wv][m16][kf * 32 + quad * 8];
        #pragma unroll
        for (int it = 0; it < 2; it++)
            sacc[it] = __builtin_amdgcn_mfma_f32_16x16x32_bf16(
                abnd[it][kf], bfr, sacc[it], 0, 0, 0);
    }
    // scatter S (i = it*16+quad*4+rg, q = m16); rows 26..31 are dead
    #pragma unroll
    for (int it = 0; it < 2; it++)
        #pragma unroll
        for (int rg = 0; rg < 4; rg++)
            Sc[wv][it * 16 + quad * 4 + rg][m16] = sacc[it][rg];

    // ---- softmax over band i in [q, q+10] of column q=m16 ----
    // (redundant across quads; broadcast LDS reads; lane rr holds row rw+rr's p)
    float p[WINDOW];
    {
        float s[WINDOW];
        float mx = -1e30f;
        #pragma unroll
        for (int w = 0; w < WINDOW; w++) {
            s[w] = Sc[wv][m16 + w][m16];
            mx = fmaxf(mx, s[w]);
        }
        float den = 0.0f;
        #pragma unroll
        for (int w = 0; w < WINDOW; w++) {
            p[w] = __expf((s[w] - mx) * 0.125f);  // 1/sqrt(64) folded in
            den += p[w];
        }
        const float rden = __fdividef(1.0f, den);
        #pragma unroll
        for (int w = 0; w < WINDOW; w++) p[w] *= rden;
    }

    // ---- P4: out[rw+rr][lane] = sum_w p[rr][w] * A[rw+rr-5+w][lane] ----
    float aw[26];  // fp32 window, coalesced dword loads, uniform guards
    #pragma unroll
    for (int s = 0; s < 26; s++) {
        const int gr = rw - PAD + s;
        aw[s] = ((unsigned)gr < (unsigned)rows)
                    ? A[(size_t)gr * RANK + lane] : 0.0f;
    }
    #pragma unroll
    for (int rr = 0; rr < TILE; rr++) {
        float o = 0.0f;
        #pragma unroll
        for (int w = 0; w < WINDOW; w++) {
            const float pw = __uint_as_float(
                __builtin_amdgcn_readlane(__float_as_uint(p[w]), rr));
            o = fmaf(pw, aw[rr + w], o);
        }
        if (rw + rr < rows)
            out[(size_t)(rw + rr) * RANK + lane] = o;
    }
}

extern "C" void kernel_launch(void* const* d_in, const int* in_sizes, int n_in,
                              void* d_out, int out_size, void* d_ws, size_t ws_size,
                              hipStream_t stream) {
    const float* A = (const float*)d_in[0];
    const float* W = (const float*)d_in[1];
    const float* b = (const float*)d_in[2];
    float* out = (float*)d_out;

    const int rows   = in_sizes[0] / RANK;
    const int blocks = (rows + TR - 1) / TR;   // one 64-row tile per block

    hipLaunchKernelGGL(attn_win_kernel, dim3(blocks), dim3(BLOCK), 0, stream,
                       A, W, b, out, rows);
}